// Round 4
// baseline (444.505 us; speedup 1.0000x reference)
//
#include <hip/hip_runtime.h>
#include <math.h>

// Problem constants (fixed by setup_inputs)
constexpr int KV_LEN    = 4096;
constexpr int PAGE_SZ   = 16;
constexpr int SHIFT     = 16;
constexpr int BSZ       = 4;
constexpr int SEQ_LEN   = 512;
constexpr int HEADS     = 16;
constexpr int HEAD_DIM  = 128;
constexpr int PAGES     = BSZ * KV_LEN / PAGE_SZ;  // 1024
constexpr int PPS       = PAGES / BSZ;             // 256 pages per sequence
constexpr int KEEP      = KV_LEN - SHIFT;          // 4080
constexpr int CUT       = KEEP - SEQ_LEN;          // 3568: j<CUT -> cache[j+528]
constexpr int PAGE_STR  = 2 * PAGE_SZ * HEADS * HEAD_DIM;  // 65536 floats
constexpr int C_STR     = PAGE_SZ * HEADS * HEAD_DIM;      // 32768
constexpr int S_STR     = HEADS * HEAD_DIM;                // 2048

typedef float f32x4 __attribute__((ext_vector_type(4)));

// inv[page] = position of `page` in kv_page_indices, or -1 if absent.
// PAGES==1024 fits one block; __syncthreads orders init vs scatter.
__global__ void build_inv(const int* __restrict__ idx, int* __restrict__ inv, int n) {
    int t = threadIdx.x;
    if (t < n) inv[t] = -1;
    __syncthreads();
    if (t < n) inv[idx[t]] = t;
}

// One block per (page, s) slab-pair: k-half + v-half = 2 x 2048 floats (16 KB).
// 256 threads; each thread owns the RoPE pair (d0..d0+3, d0+64..d0+67) in BOTH
// the k and v halves -> 4x float4 NT loads + 4x float4 NT stores = 128 B/thread.
// Scalar source-resolution (inv -> pidx chain) runs ONCE per (page,s), not twice.
// Trig: ONE sincos per lane (freq = lane), distributed via __shfl — bitwise
// identical to per-thread sincosf. Bulk traffic is read-once/write-once ->
// nontemporal to keep it out of L2. (Resubmit of the R2/R3 source: both prior
// failures were container-acquisition errors, not kernel faults.)
__global__ __launch_bounds__(256) void kv_shift_rope(
    const float* __restrict__ kin, const float* __restrict__ vin,
    const float* __restrict__ dc,  const int*  __restrict__ pidx,
    const int*  __restrict__ inv,  float* __restrict__ out)
{
    int blk = blockIdx.x;          // PAGES*PAGE_SZ = 16384
    int p   = blk >> 4;
    int s   = blk & 15;

    int tid = threadIdx.x;
    int h   = tid >> 4;
    int d0  = (tid & 15) << 2;     // 0..60 step 4

    int off1 = h * HEAD_DIM + d0;
    int off2 = off1 + 64;

    float* opk = out + (size_t)p * PAGE_STR + s * S_STR;
    float* opv = opk + C_STR;

    int pos = inv[p];              // block-uniform
    const float *spk, *spv;
    int j = 0;
    if (pos < 0) {
        // page not updated: passthrough copy (no RoPE — reference leaves
        // non-indexed pages untouched)
        spk = dc + (size_t)p * PAGE_STR + s * S_STR;
        spv = spk + C_STR;
    } else {
        int b  = pos >> 8;         // /PPS (256)
        int pp = pos & (PPS - 1);
        j = pp * PAGE_SZ + s;      // absolute sequence position, 0..4095
        if (j >= CUT && j < KEEP) {
            // sourced from the new k/v tensors
            size_t o = (size_t)(b * SEQ_LEN + (j - CUT)) * S_STR;
            spk = kin + o;
            spv = vin + o;
        } else {
            // sourced from the old cache (shifted window or retained tail)
            int t2 = (j < CUT) ? (j + SHIFT + SEQ_LEN) : j;
            int q  = t2 >> 4;
            int ss = t2 & 15;
            int srcpage = pidx[b * PPS + q];
            spk = dc + (size_t)srcpage * PAGE_STR + ss * S_STR;
            spv = spk + C_STR;
        }
    }

    // Issue all four long-pole loads first; trig executes under their latency.
    f32x4 k1 = __builtin_nontemporal_load((const f32x4*)(spk + off1));
    f32x4 k2 = __builtin_nontemporal_load((const f32x4*)(spk + off2));
    f32x4 v1 = __builtin_nontemporal_load((const f32x4*)(spv + off1));
    f32x4 v2 = __builtin_nontemporal_load((const f32x4*)(spv + off2));

    if (pos >= 0) {
        // RoPE (neox rotate-half) on the k-half at position j, fp32.
        // Lane L computes sincos for frequency index L; shfl distributes.
        const float neg_log2_theta_over_half = -0.20762050593046939f; // -log2(10000)/64
        int   lane  = tid & 63;
        float invf  = exp2f((float)lane * neg_log2_theta_over_half);
        float sn_l, cs_l;
        sincosf((float)j * invf, &sn_l, &cs_l);

        float cs[4], sn[4];
        #pragma unroll
        for (int i = 0; i < 4; i++) {
            cs[i] = __shfl(cs_l, d0 + i);
            sn[i] = __shfl(sn_l, d0 + i);
        }

        f32x4 o1, o2;
        #pragma unroll
        for (int i = 0; i < 4; i++) {
            o1[i] = k1[i] * cs[i] - k2[i] * sn[i];
            o2[i] = k1[i] * sn[i] + k2[i] * cs[i];
        }
        __builtin_nontemporal_store(o1, (f32x4*)(opk + off1));
        __builtin_nontemporal_store(o2, (f32x4*)(opk + off2));
    } else {
        __builtin_nontemporal_store(k1, (f32x4*)(opk + off1));
        __builtin_nontemporal_store(k2, (f32x4*)(opk + off2));
    }

    // v-half: always passthrough (RoPE applies to k only)
    __builtin_nontemporal_store(v1, (f32x4*)(opv + off1));
    __builtin_nontemporal_store(v2, (f32x4*)(opv + off2));
}

extern "C" void kernel_launch(void* const* d_in, const int* in_sizes, int n_in,
                              void* d_out, int out_size, void* d_ws, size_t ws_size,
                              hipStream_t stream) {
    const float* kin  = (const float*)d_in[0];
    const float* vin  = (const float*)d_in[1];
    const float* dc   = (const float*)d_in[2];
    const int*   pidx = (const int*)d_in[3];
    int pages = in_sizes[3];           // 1024

    int* inv = (int*)d_ws;             // 4 KB scratch
    build_inv<<<1, pages, 0, stream>>>(pidx, inv, pages);

    int grid = PAGES * PAGE_SZ;        // 16384 blocks (k+v fused per block)
    kv_shift_rope<<<grid, 256, 0, stream>>>(kin, vin, dc, pidx, inv, (float*)d_out);
}